// Round 1
// baseline (281.441 us; speedup 1.0000x reference)
//
#include <hip/hip_runtime.h>
#include <hip/hip_bf16.h>

typedef __attribute__((ext_vector_type(8))) short bf16x8;
typedef __attribute__((ext_vector_type(4))) float f32x4;

#define KDIM 512
#define NDIM 512
#define BM 128
#define BN 128
#define BK 64
#define NT (KDIM / BK) // 8

__device__ __forceinline__ unsigned int pack_bf16(float a, float b) {
  // values are exact integers |v|<=128 -> low 16 bits of f32 are zero, truncation exact
  return (__builtin_bit_cast(unsigned int, a) >> 16) |
         (__builtin_bit_cast(unsigned int, b) & 0xffff0000u);
}

// ---------------- weight quantization (512 rows, 1 wave each) ----------------
__global__ __launch_bounds__(64)
void quant_w_kernel(const float* __restrict__ W, const float* __restrict__ bias,
                    const float* __restrict__ scale_x,
                    ushort* __restrict__ Wq, float* __restrict__ bq,
                    float* __restrict__ so_out) {
  const int n = blockIdx.x;
  const int l = threadIdx.x;
  const float* row = W + (size_t)n * KDIM;
  float4 v0 = *(const float4*)(row + l * 8);
  float4 v1 = *(const float4*)(row + l * 8 + 4);
  float m = fmaxf(fmaxf(fmaxf(fabsf(v0.x), fabsf(v0.y)), fmaxf(fabsf(v0.z), fabsf(v0.w))),
                  fmaxf(fmaxf(fabsf(v1.x), fabsf(v1.y)), fmaxf(fabsf(v1.z), fabsf(v1.w))));
#pragma unroll
  for (int off = 32; off; off >>= 1) m = fmaxf(m, __shfl_xor(m, off, 64));
  const float scale = fmaxf(m, 1e-8f) / 127.0f; // IEEE f32 div, matches jnp
  float vals[8] = {v0.x, v0.y, v0.z, v0.w, v1.x, v1.y, v1.z, v1.w};
  unsigned int packed[4];
#pragma unroll
  for (int i = 0; i < 4; ++i) {
    // rintf = round-half-even = jnp.round; clip after round like reference
    float qa = fminf(fmaxf(rintf(vals[2 * i] / scale), -128.f), 127.f);
    float qb = fminf(fmaxf(rintf(vals[2 * i + 1] / scale), -128.f), 127.f);
    packed[i] = pack_bf16(qa, qb);
  }
  *(uint4*)(Wq + (size_t)n * KDIM + (size_t)l * 8) =
      make_uint4(packed[0], packed[1], packed[2], packed[3]);
  if (l == 0) {
    float so = scale * scale_x[0];
    so_out[n] = so;
    bq[n] = rintf(bias[n] / so); // |b_q| ~ 1e3-1e5 << 2^31, clip never active
  }
}

// ---------------- GEMM: C[m][n] = sum_k X[m][k] * Wq[n][k] + bq[n] ----------------
__global__ __launch_bounds__(256, 2)
void gemm_kernel(const float* __restrict__ X, const ushort* __restrict__ Wq,
                 const float* __restrict__ bq, float* __restrict__ Out) {
  __shared__ __align__(16) ushort As[2][BM * BK];
  __shared__ __align__(16) ushort Bs[2][BN * BK];

  const int nblk = gridDim.x;
  int swz = blockIdx.x;
  if ((nblk & 7) == 0) { // XCD-chunked bijective swizzle (T1)
    swz = (blockIdx.x & 7) * (nblk >> 3) + (blockIdx.x >> 3);
  }
  const int bm = swz >> 2; // N/BN = 4 tiles in n
  const int bn = swz & 3;

  const int tid = threadIdx.x;
  const int l = tid & 63, w = tid >> 6;
  const int wr = w >> 1, wc = w & 1;
  const int lr = l & 15, lk = l >> 4;

  const float* xbase = X + (size_t)bm * BM * KDIM;
  const ushort* wbase = Wq + (size_t)bn * BN * KDIM;

  float4 av[8];
  f32x4 acc[4][4];
#pragma unroll
  for (int i = 0; i < 4; ++i)
#pragma unroll
    for (int j = 0; j < 4; ++j) acc[i][j] = (f32x4){0.f, 0.f, 0.f, 0.f};

  auto loadA = [&](int t) { // issue 8 coalesced float4 loads into regs
#pragma unroll
    for (int i = 0; i < 8; ++i) {
      int e = i * 256 + tid;
      int row = e >> 4, c4 = e & 15;
      av[i] = *(const float4*)(xbase + (size_t)row * KDIM + t * BK + c4 * 4);
    }
  };
  auto writeA = [&](int buf) { // cvt f32->bf16, swizzled ds_write_b64 (T2)
    char* sA = (char*)&As[buf][0];
#pragma unroll
    for (int i = 0; i < 8; ++i) {
      int e = i * 256 + tid;
      int row = e >> 4, c4 = e & 15;
      int byteo = (row * 128 + c4 * 8) ^ ((row & 7) << 4);
      uint2 p;
      p.x = pack_bf16(av[i].x, av[i].y);
      p.y = pack_bf16(av[i].z, av[i].w);
      *(uint2*)(sA + byteo) = p;
    }
  };
  auto stageB = [&](int t, int buf) { // global_load_lds w/ pre-swizzled source (m173)
#pragma unroll
    for (int i = 0; i < 4; ++i) {
      int c = w * 4 + i;      // 1KB wave-chunk: LDS dest = base + lane*16 (linear)
      int s = c * 64 + l;     // 16B slot
      int row = s >> 3, kc = s & 7;
      int skc = kc ^ (row & 7); // inverse-swizzle the SOURCE, keep dest linear
      const ushort* g = wbase + (size_t)row * KDIM + t * BK + skc * 8;
      ushort* lp = &Bs[buf][0] + (size_t)s * 8;
      __builtin_amdgcn_global_load_lds(
          (const __attribute__((address_space(1))) unsigned int*)g,
          (__attribute__((address_space(3))) unsigned int*)lp, 16, 0, 0);
    }
  };
  auto compute = [&](int buf) {
    const char* pA = (const char*)&As[buf][0];
    const char* pB = (const char*)&Bs[buf][0];
#pragma unroll
    for (int ks = 0; ks < 2; ++ks) {
      bf16x8 af[4], bfr[4];
#pragma unroll
      for (int mf = 0; mf < 4; ++mf) {
        int row = wr * 64 + mf * 16 + lr;
        int byteo = (row * 128 + (ks * 4 + lk) * 16) ^ ((row & 7) << 4);
        af[mf] = *(const bf16x8*)(pA + byteo);
      }
#pragma unroll
      for (int nf = 0; nf < 4; ++nf) {
        int row = wc * 64 + nf * 16 + lr;
        int byteo = (row * 128 + (ks * 4 + lk) * 16) ^ ((row & 7) << 4);
        bfr[nf] = *(const bf16x8*)(pB + byteo);
      }
#pragma unroll
      for (int mf = 0; mf < 4; ++mf)
#pragma unroll
        for (int nf = 0; nf < 4; ++nf)
          acc[mf][nf] = __builtin_amdgcn_mfma_f32_16x16x32_bf16(
              af[mf], bfr[nf], acc[mf][nf], 0, 0, 0);
    }
  };

  // ---- 2-phase pipeline (T3 minimal recipe) ----
  stageB(0, 0);
  loadA(0);
  writeA(0);
  __syncthreads();

  int cur = 0;
  for (int t = 0; t < NT; ++t) {
    if (t < NT - 1) {
      stageB(t + 1, cur ^ 1); // issue next-tile loads BEFORE compute
      loadA(t + 1);
    }
    compute(cur);
    if (t < NT - 1) writeA(cur ^ 1); // compiler inserts vmcnt wait before first use
    __syncthreads();                 // drains vmcnt+lgkm (B lds-loads + A ds_writes)
    cur ^= 1;
  }

  // ---- epilogue: D row = lk*4+e, col = lr (m89-verified C/D layout) ----
  const size_t m0 = (size_t)bm * BM + (size_t)wr * 64;
  const int n0 = bn * BN + wc * 64;
#pragma unroll
  for (int nf = 0; nf < 4; ++nf) {
    const int col = n0 + nf * 16 + lr;
    const float bqv = bq[col];
#pragma unroll
    for (int mf = 0; mf < 4; ++mf) {
      const size_t rbase = m0 + (size_t)mf * 16 + (size_t)lk * 4;
#pragma unroll
      for (int e = 0; e < 4; ++e)
        Out[(rbase + e) * NDIM + col] = acc[mf][nf][e] + bqv;
    }
  }
}

extern "C" void kernel_launch(void* const* d_in, const int* in_sizes, int n_in,
                              void* d_out, int out_size, void* d_ws, size_t ws_size,
                              hipStream_t stream) {
  const float* x = (const float*)d_in[0];
  const float* weight = (const float*)d_in[1];
  const float* bias = (const float*)d_in[2];
  const float* scale_x = (const float*)d_in[3];
  const int M = in_sizes[0] / KDIM; // 65536

  float* out = (float*)d_out;
  float* so_out = out + (size_t)M * NDIM; // scale_out tail of the tuple
  ushort* Wq = (ushort*)d_ws;
  float* bq = (float*)((char*)d_ws + (size_t)NDIM * KDIM * sizeof(ushort));

  quant_w_kernel<<<NDIM, 64, 0, stream>>>(weight, bias, scale_x, Wq, bq, so_out);

  const int blocks = (M / BM) * (NDIM / BN); // 2048
  gemm_kernel<<<blocks, 256, 0, stream>>>(x, Wq, bq, out);
}